// Round 12
// baseline (47.085 us; speedup 1.0000x reference)
//
#include <hip/hip_runtime.h>

// UVFA_text r12: two 8-wave blocks per CU (grid 512x512), overlapped tracks.
//  pack: Whh/Wih -> f16 transposed; Ws2 -> u32 f16-pairs.
//  k1 blocks 0..255  : LSTM(b) -> wsH      (1 barrier/step, all-wave nonlin)
//     blocks 256..511: objMLP(b)->wsO3 ; base_s ; h1P staging -> wsH1
//  k2 (256 blocks)   : w=o3*h -> u,c0 ; LDS copies ; P8 MFMA -> out

#define B_   256
#define M2_  100
#define R_   128
#define L_   12
#define E_   64

typedef _Float16 half2v __attribute__((ext_vector_type(2)));
typedef _Float16 f16x8  __attribute__((ext_vector_type(8)));
typedef float    f32x4  __attribute__((ext_vector_type(4)));

__device__ __forceinline__ float sigf(float x) { return 1.f / (1.f + expf(-x)); }

__device__ __forceinline__ uint pk16(float a, float b) {
    half2v h; h.x = (_Float16)a; h.y = (_Float16)b;
    return __builtin_bit_cast(uint, h);
}

#define PINU4(v) asm volatile("" : "+v"(v.x), "+v"(v.y), "+v"(v.z), "+v"(v.w));

// ---- pack: WhhT16[c][r] (512x128 f16), WihT16[c][e] (512x64 f16), Ws2 u32 pairs ----
__global__ __launch_bounds__(256) void pack_kernel(
    const float* __restrict__ Whh, const float* __restrict__ Wih,
    const float* __restrict__ Ws2, void* __restrict__ wsv)
{
    _Float16* WhhT = (_Float16*)wsv;            // [512][128]
    _Float16* WihT = WhhT + 65536;              // [512][64]
    uint*     W2P  = (uint*)(WihT + 32768);     // [64][128]
    int g = blockIdx.x * 256 + threadIdx.x;
    if (g < 65536) {
        int r = g >> 9, c = g & 511;
        WhhT[c * 128 + r] = (_Float16)Whh[r * 512 + c];
    } else if (g < 65536 + 32768) {
        int g2 = g - 65536;
        int e = g2 >> 9, c = g2 & 511;
        WihT[c * 64 + e] = (_Float16)Wih[e * 512 + c];
    } else if (g < 65536 + 32768 + 8192) {
        int g3 = g - 65536 - 32768;
        int jp = g3 >> 7, kk = g3 & 127;
        W2P[g3] = pk16(Ws2[(2 * jp) * R_ + kk], Ws2[(2 * jp + 1) * R_ + kk]);
    }
}

// ================= k1: LSTM track + prep track, 2 blocks/CU =================
__global__ __launch_bounds__(512) __attribute__((amdgpu_waves_per_eu(4, 4)))
void k1_kernel(
    const int* __restrict__ state, const int* __restrict__ obj, const int* __restrict__ text,
    const float* __restrict__ Ws1, const float* __restrict__ bs1,
    const float* __restrict__ Wo1, const float* __restrict__ bo1,
    const float* __restrict__ Wo2, const float* __restrict__ bo2,
    const float* __restrict__ Wo3, const float* __restrict__ bo3,
    const float* __restrict__ emb, const float* __restrict__ b_lstm,
    const _Float16* __restrict__ WhhT, const _Float16* __restrict__ WihT,
    float* __restrict__ wsH, float* __restrict__ wsO3, uint* __restrict__ wsH1)
{
    const int tid = threadIdx.x;
    __shared__ __align__(16) uint  U[7232];          // xw f32 [12][512] + xemb f32 [16][68]
    __shared__ __align__(16) uint  hpair[2][64];
    __shared__ __align__(16) float part[512];
    __shared__ __align__(16) float tmp[R_], tmp2[R_], bsb[R_];
    __shared__ int idx[M2_], tids[L_];

    if (blockIdx.x < 256) {
        // ---------------- LSTM track ----------------
        const int b    = blockIdx.x;
        const int lane = tid & 63;
        const int wv   = tid >> 6;          // 0..7
        const int m16  = lane & 15;
        const int kgrp = lane >> 4;
        float* xw   = (float*)U;            // [12][512]
        float* xemb = (float*)(U + 6144);   // [16][68]

        // A-frags: gate g tile (wv+8g); 64 VGPRs, pinned
        uint4 afu[4][4];
        #pragma unroll
        for (int g = 0; g < 4; ++g) {
            int col = (wv + 8 * g) * 16 + m16;
            #pragma unroll
            for (int s = 0; s < 4; ++s) {
                afu[g][s] = *(const uint4*)&WhhT[col * 128 + s * 32 + kgrp * 8];
                PINU4(afu[g][s])
            }
        }

        if (tid < L_) tids[tid] = text[b * L_ + tid];
        if (tid >= 64 && tid < 128) hpair[0][tid - 64] = 0u;
        __syncthreads();
        for (int i = tid; i < 16 * 68; i += 512) {
            int t = i / 68, c = i - t * 68;
            xemb[i] = (c < 64 && t < L_) ? emb[tids[t] * E_ + c] : 0.f;
        }
        __syncthreads();

        // P2: xw = b_lstm + x @ Wih via MFMA (4 tiles/wave)
        {
            f16x8 ax[2];
            #pragma unroll
            for (int s = 0; s < 2; ++s)
                #pragma unroll
                for (int e = 0; e < 8; ++e)
                    ax[s][e] = (_Float16)xemb[m16 * 68 + s * 32 + kgrp * 8 + e];
            #pragma unroll
            for (int i4 = 0; i4 < 4; ++i4) {
                int col = (wv + 8 * i4) * 16 + m16;
                float bl = b_lstm[col];
                f32x4 acc = { bl, bl, bl, bl };
                #pragma unroll
                for (int s = 0; s < 2; ++s) {
                    f16x8 bx = *(const f16x8*)&WihT[col * 64 + s * 32 + kgrp * 8];
                    acc = __builtin_amdgcn_mfma_f32_16x16x32_f16(ax[s], bx, acc, 0, 0, 0);
                }
                if (kgrp < 3) {
                    #pragma unroll
                    for (int r = 0; r < 4; ++r)
                        xw[(kgrp * 4 + r) * 512 + col] = acc[r];
                }
            }
        }
        __syncthreads();

        // LSTM: 12 steps, ONE barrier per step, nonlin fully in-lane
        float cst0 = 0.f, cst1 = 0.f, cst2 = 0.f, cst3 = 0.f;
        float h0 = 0.f, h1v = 0.f, h2v = 0.f, h3v = 0.f;
        for (int t = 0; t < L_; ++t) {
            const uint* hp = hpair[t & 1];
            f16x8 bf[4];
            #pragma unroll
            for (int s = 0; s < 4; ++s)
                bf[s] = __builtin_bit_cast(f16x8, *(const uint4*)&hp[s * 16 + kgrp * 4]);
            f32x4 acc[4];
            #pragma unroll
            for (int g = 0; g < 4; ++g) {
                acc[g] = *(const f32x4*)&xw[t * 512 + (wv + 8 * g) * 16 + kgrp * 4];
                #pragma unroll
                for (int s = 0; s < 4; ++s)
                    acc[g] = __builtin_amdgcn_mfma_f32_16x16x32_f16(
                        __builtin_bit_cast(f16x8, afu[g][s]), bf[s], acc[g], 0, 0, 0);
            }
            // acc[g][r] = gate g for j = 16*wv + 4*kgrp + r (replicated over m16)
            cst0 = sigf(acc[1][0]) * cst0 + sigf(acc[0][0]) * tanhf(acc[2][0]);
            h0   = sigf(acc[3][0]) * tanhf(cst0);
            cst1 = sigf(acc[1][1]) * cst1 + sigf(acc[0][1]) * tanhf(acc[2][1]);
            h1v  = sigf(acc[3][1]) * tanhf(cst1);
            cst2 = sigf(acc[1][2]) * cst2 + sigf(acc[0][2]) * tanhf(acc[2][2]);
            h2v  = sigf(acc[3][2]) * tanhf(cst2);
            cst3 = sigf(acc[1][3]) * cst3 + sigf(acc[0][3]) * tanhf(acc[2][3]);
            h3v  = sigf(acc[3][3]) * tanhf(cst3);
            if (m16 == 0) {
                uint* hw = hpair[(t + 1) & 1];
                hw[8 * wv + kgrp * 2]     = pk16(h0, h1v);
                hw[8 * wv + kgrp * 2 + 1] = pk16(h2v, h3v);
            }
            __syncthreads();
        }
        if (m16 == 0) {
            int j = wv * 16 + kgrp * 4;
            wsH[b * R_ + j + 0] = h0;
            wsH[b * R_ + j + 1] = h1v;
            wsH[b * R_ + j + 2] = h2v;
            wsH[b * R_ + j + 3] = h3v;
        }

    } else {
        // ---------------- prep track: obj MLP, base_s, h1 staging ----------------
        const int b = blockIdx.x - 256;
        const int k = tid & 127, qq = tid >> 7;   // qq 0..3
        if (tid < M2_) idx[tid] = obj[b * M2_ + tid];
        __syncthreads();
        {
            float a = 0.f;
            #pragma unroll 5
            for (int c = qq * 25; c < qq * 25 + 25; ++c)
                a += Wo1[(c * 32 + idx[c]) * R_ + k];
            part[qq * R_ + k] = a;
        }
        __syncthreads();
        if (tid < R_)
            tmp[tid] = fmaxf(bo1[tid] + part[tid] + part[R_ + tid] + part[2 * R_ + tid] + part[3 * R_ + tid], 0.f);
        __syncthreads();
        {
            float s0 = 0.f, s1 = 0.f, s2 = 0.f, s3 = 0.f;
            int j0 = qq * 32;
            #pragma unroll
            for (int j = 0; j < 32; j += 4) {
                s0 = fmaf(tmp[j0 + j + 0], Wo2[(j0 + j + 0) * R_ + k], s0);
                s1 = fmaf(tmp[j0 + j + 1], Wo2[(j0 + j + 1) * R_ + k], s1);
                s2 = fmaf(tmp[j0 + j + 2], Wo2[(j0 + j + 2) * R_ + k], s2);
                s3 = fmaf(tmp[j0 + j + 3], Wo2[(j0 + j + 3) * R_ + k], s3);
            }
            part[qq * R_ + k] = (s0 + s1) + (s2 + s3);
        }
        __syncthreads();
        if (tid < R_)
            tmp2[tid] = fmaxf(bo2[tid] + part[tid] + part[R_ + tid] + part[2 * R_ + tid] + part[3 * R_ + tid], 0.f);
        __syncthreads();
        {
            float s0 = 0.f, s1 = 0.f, s2 = 0.f, s3 = 0.f;
            int j0 = qq * 32;
            #pragma unroll
            for (int j = 0; j < 32; j += 4) {
                s0 = fmaf(tmp2[j0 + j + 0], Wo3[(j0 + j + 0) * R_ + k], s0);
                s1 = fmaf(tmp2[j0 + j + 1], Wo3[(j0 + j + 1) * R_ + k], s1);
                s2 = fmaf(tmp2[j0 + j + 2], Wo3[(j0 + j + 2) * R_ + k], s2);
                s3 = fmaf(tmp2[j0 + j + 3], Wo3[(j0 + j + 3) * R_ + k], s3);
            }
            part[qq * R_ + k] = (s0 + s1) + (s2 + s3);
        }
        __syncthreads();
        if (tid < R_)
            wsO3[b * R_ + tid] = bo3[tid] + part[tid] + part[R_ + tid] + part[2 * R_ + tid] + part[3 * R_ + tid];
        __syncthreads();
        // base_s gather (reuse idx/part)
        if (tid < M2_) idx[tid] = state[b * M2_ + tid];
        __syncthreads();
        {
            float a = 0.f;
            #pragma unroll 5
            for (int c = qq * 25; c < qq * 25 + 25; ++c)
                a += Ws1[(c * 33 + idx[c]) * R_ + k];
            part[qq * R_ + k] = a;
        }
        __syncthreads();
        if (tid < R_)
            bsb[tid] = bs1[tid] + part[tid] + part[R_ + tid] + part[2 * R_ + tid] + part[3 * R_ + tid];
        __syncthreads();
        // h1P staging -> global ws, f16 pairs, [p][jp] with row stride 68
        #pragma unroll 5
        for (int pass = 0; pass < 25; ++pass) {
            int id2 = pass * 512 + tid;
            int j = id2 & 127, p = id2 >> 7;
            float v = fmaxf(bsb[j] + Ws1[(p * 33 + 32) * R_ + j], 0.f);
            float v2 = __shfl_down(v, 1, 64);
            if (!(j & 1)) wsH1[(size_t)b * 7616 + p * 68 + (j >> 1)] = pk16(v, v2);
        }
    }
}

// ================= k2: join + P8 MFMA =================
__global__ __launch_bounds__(512)
void k2_kernel(
    const float* __restrict__ bs2, const float* __restrict__ Ws3,
    const float* __restrict__ bs3, const uint* __restrict__ W2P,
    const float* __restrict__ wsH, const float* __restrict__ wsO3,
    const uint* __restrict__ wsH1,
    float* __restrict__ out)
{
    const int b   = blockIdx.x;
    const int tid = threadIdx.x;

    // U: Ws2P u32 [64][132] = 0..8447 ; h1P u32 [112][68] = 8448..16063
    __shared__ __align__(16) uint  U[16064];
    __shared__ __align__(16) float part[512];
    __shared__ __align__(16) float wbuf[R_], ubuf[R_];
    __shared__ float redw[112];
    __shared__ float c0s;

    const int lane = tid & 63;
    const int wv   = tid >> 6;     // 0..7
    const int m16  = lane & 15;
    const int kgrp = lane >> 4;
    const int k = tid & 127, qq = tid >> 7;   // 0..3

    // phase 1: w, Ws2P copy, h1P copy (independent)
    if (tid < R_) wbuf[tid] = wsH[b * R_ + tid] * wsO3[b * R_ + tid];
    {
        const uint4* src = (const uint4*)W2P;
        #pragma unroll
        for (int i = tid; i < 2048; i += 512) {
            uint4 v = src[i];
            int jp = i >> 5, kq = i & 31;
            *(uint4*)&U[jp * 132 + kq * 4] = v;
        }
    }
    {
        const uint4* hsrc = (const uint4*)(wsH1 + (size_t)b * 7616);
        uint4* hdst = (uint4*)(U + 8448);
        #pragma unroll 4
        for (int i = tid; i < 1700; i += 512) hdst[i] = hsrc[i];
    }
    __syncthreads();

    // phase 2: u partials + c0
    {
        float s0 = 0.f, s1 = 0.f, s2 = 0.f, s3 = 0.f;
        const float4* w4 = reinterpret_cast<const float4*>(&Ws3[k * R_ + qq * 32]);
        #pragma unroll
        for (int jj = 0; jj < 8; ++jj) {
            float4 v = w4[jj];
            int j0 = qq * 32 + jj * 4;
            s0 = fmaf(v.x, wbuf[j0 + 0], s0);
            s1 = fmaf(v.y, wbuf[j0 + 1], s1);
            s2 = fmaf(v.z, wbuf[j0 + 2], s2);
            s3 = fmaf(v.w, wbuf[j0 + 3], s3);
        }
        part[qq * R_ + k] = (s0 + s1) + (s2 + s3);
    }
    if (tid >= 448) {
        int j = tid - 448;
        float s = bs3[j] * wbuf[j] + bs3[j + 64] * wbuf[j + 64];
        s += __shfl_down(s, 32, 64);
        s += __shfl_down(s, 16, 64);
        s += __shfl_down(s, 8, 64);
        s += __shfl_down(s, 4, 64);
        s += __shfl_down(s, 2, 64);
        s += __shfl_down(s, 1, 64);
        if (j == 0) c0s = s;
    }
    __syncthreads();
    if (tid < R_)
        ubuf[tid] = part[tid] + part[R_ + tid] + part[2 * R_ + tid] + part[3 * R_ + tid];
    __syncthreads();

    // P8: wave wv<7 = mtile, all 8 col-tiles (32 MFMA/wave)
    if (wv < 7) {
        const uint* Ap = U + 8448 + (wv * 16 + m16) * 68;
        f16x8 A[4];
        #pragma unroll
        for (int s = 0; s < 4; ++s)
            A[s] = __builtin_bit_cast(f16x8, *(const uint4*)&Ap[s * 16 + kgrp * 4]);
        f32x4 acc[8];
        #pragma unroll
        for (int nt = 0; nt < 8; ++nt) acc[nt] = f32x4{ 0.f, 0.f, 0.f, 0.f };
        #pragma unroll
        for (int nt = 0; nt < 8; ++nt) {
            int ko = nt * 16 + m16;
            #pragma unroll
            for (int s = 0; s < 4; ++s) {
                const uint* Bp = U + (s * 16 + kgrp * 4) * 132 + ko;
                uint4 bv = { Bp[0], Bp[132], Bp[264], Bp[396] };
                acc[nt] = __builtin_amdgcn_mfma_f32_16x16x32_f16(
                    A[s], __builtin_bit_cast(f16x8, bv), acc[nt], 0, 0, 0);
            }
        }
        float vs0 = 0.f, vs1 = 0.f, vs2 = 0.f, vs3 = 0.f;
        #pragma unroll
        for (int nt = 0; nt < 8; ++nt) {
            int ko = nt * 16 + m16;
            float bb = bs2[ko], uu = ubuf[ko];
            vs0 = fmaf(fmaxf(acc[nt][0] + bb, 0.f), uu, vs0);
            vs1 = fmaf(fmaxf(acc[nt][1] + bb, 0.f), uu, vs1);
            vs2 = fmaf(fmaxf(acc[nt][2] + bb, 0.f), uu, vs2);
            vs3 = fmaf(fmaxf(acc[nt][3] + bb, 0.f), uu, vs3);
        }
        vs0 += __shfl_xor(vs0, 1, 64); vs0 += __shfl_xor(vs0, 2, 64);
        vs0 += __shfl_xor(vs0, 4, 64); vs0 += __shfl_xor(vs0, 8, 64);
        vs1 += __shfl_xor(vs1, 1, 64); vs1 += __shfl_xor(vs1, 2, 64);
        vs1 += __shfl_xor(vs1, 4, 64); vs1 += __shfl_xor(vs1, 8, 64);
        vs2 += __shfl_xor(vs2, 1, 64); vs2 += __shfl_xor(vs2, 2, 64);
        vs2 += __shfl_xor(vs2, 4, 64); vs2 += __shfl_xor(vs2, 8, 64);
        vs3 += __shfl_xor(vs3, 1, 64); vs3 += __shfl_xor(vs3, 2, 64);
        vs3 += __shfl_xor(vs3, 4, 64); vs3 += __shfl_xor(vs3, 8, 64);
        if (m16 == 0) {
            int pr = wv * 16 + kgrp * 4;
            redw[pr + 0] = vs0;
            redw[pr + 1] = vs1;
            redw[pr + 2] = vs2;
            redw[pr + 3] = vs3;
        }
    }
    __syncthreads();

    if (tid < M2_)
        out[b * M2_ + tid] = c0s + redw[tid];
}

extern "C" void kernel_launch(void* const* d_in, const int* in_sizes, int n_in,
                              void* d_out, int out_size, void* d_ws, size_t ws_size,
                              hipStream_t stream) {
    const int*   state  = (const int*)d_in[0];
    const int*   obj    = (const int*)d_in[1];
    const int*   text   = (const int*)d_in[2];
    const float* Ws1    = (const float*)d_in[3];
    const float* bs1    = (const float*)d_in[4];
    const float* Ws2    = (const float*)d_in[5];
    const float* bs2    = (const float*)d_in[6];
    const float* Ws3    = (const float*)d_in[7];
    const float* bs3    = (const float*)d_in[8];
    const float* Wo1    = (const float*)d_in[9];
    const float* bo1    = (const float*)d_in[10];
    const float* Wo2    = (const float*)d_in[11];
    const float* bo2    = (const float*)d_in[12];
    const float* Wo3    = (const float*)d_in[13];
    const float* bo3    = (const float*)d_in[14];
    const float* emb    = (const float*)d_in[15];
    const float* Wih    = (const float*)d_in[16];
    const float* Whh    = (const float*)d_in[17];
    const float* b_lstm = (const float*)d_in[18];
    float* out = (float*)d_out;

    _Float16* WhhT = (_Float16*)d_ws;           // 65536 f16
    _Float16* WihT = WhhT + 65536;              // 32768 f16
    uint*     W2P  = (uint*)(WihT + 32768);     // 8192 u32
    float*    wsH  = (float*)(W2P + 8192);      // 256*128 f32
    float*    wsO3 = wsH + 32768;               // 256*128 f32
    uint*     wsH1 = (uint*)(wsO3 + 32768);     // 256*7616 u32

    hipLaunchKernelGGL(pack_kernel, dim3(416), dim3(256), 0, stream, Whh, Wih, Ws2, d_ws);
    hipLaunchKernelGGL(k1_kernel, dim3(512), dim3(512), 0, stream,
                       state, obj, text, Ws1, bs1,
                       Wo1, bo1, Wo2, bo2, Wo3, bo3, emb, b_lstm,
                       WhhT, WihT, wsH, wsO3, wsH1);
    hipLaunchKernelGGL(k2_kernel, dim3(B_), dim3(512), 0, stream,
                       bs2, Ws3, bs3, W2P, wsH, wsO3, wsH1, out);
}